// Round 18
// baseline (196.614 us; speedup 1.0000x reference)
//
#include <hip/hip_runtime.h>
#include <math.h>

#define B_    16
#define C_    256
#define H_    64
#define W_    64
#define N_    4096
#define HEADS_ 4
#define KK_   16
#define VV_   64
#define M_    7
#define PAD_  3
#define OTOT_ 144   // 64 q + 16 k + 64 v channels
#define NG_   36    // 36 groups of 4 channels
#define EPS_  1e-5f

typedef __attribute__((ext_vector_type(8))) short short8b;
typedef __attribute__((ext_vector_type(4))) float f32x4;

// bf16 helpers (round-half-up; error ~2^-9 relative, fine vs threshold)
__device__ inline unsigned packbf(float a, float b) {
  unsigned ua = __float_as_uint(a) + 0x8000u;
  unsigned ub = __float_as_uint(b) + 0x8000u;
  return (ua >> 16) | (ub & 0xffff0000u);
}
__device__ inline float bflo(unsigned u) { return __uint_as_float(u << 16); }
__device__ inline float bfhi(unsigned u) { return __uint_as_float(u & 0xffff0000u); }

// ---------------------------------------------------------------------------
// K0: convert wq/wk/wv -> bf16 wbf[144][256] (row-major o-major).
// ---------------------------------------------------------------------------
__global__ __launch_bounds__(256) void k_wcvt(const float* __restrict__ wq,
    const float* __restrict__ wk, const float* __restrict__ wv,
    unsigned short* __restrict__ wbf) {
  const int idx = blockIdx.x * 256 + threadIdx.x;   // grid 144 -> 36864
  if (idx >= OTOT_ * C_) return;
  const int o = idx >> 8, c = idx & 255;
  const float* wrow = (o < 64) ? (wq + o * C_)
                     : ((o < 80) ? (wk + (o - 64) * C_) : (wv + (o - 80) * C_));
  wbf[idx] = (unsigned short)((__float_as_uint(wrow[c]) + 0x8000u) >> 16);
}

// ---------------------------------------------------------------------------
// K1 v7: MFMA projection GEMM with register-prefetch software pipeline.
// proj[b,o,n] = sum_c W[o,c]*x[b,c,n], bf16 in / fp32 accum.
// Block = 4 waves, out-tile 144 x 64 px. Per K-step(32): pack prefetched
// regs -> LDS, issue NEXT step's 8 loads, barrier, 9 MFMAs. 1 barrier/step.
// ---------------------------------------------------------------------------
__global__ __launch_bounds__(256) void k_proj_mfma(const float* __restrict__ x,
    const unsigned short* __restrict__ wbf, float* __restrict__ proj) {
  const int pt = blockIdx.x;       // 0..63 px-tile (64 px)
  const int b  = blockIdx.y;
  const int px0 = pt * 64;
  const int tid = threadIdx.x;
  const int w    = tid >> 6;       // wave id
  const int lane = tid & 63;
  const int ln15 = lane & 15;
  const int lg   = lane >> 4;      // k-group 0..3

  __shared__ unsigned short s_x[2][2048];   // [buf][kg*512 + px*8]

  const int spx = tid & 63;
  const int skg = tid >> 6;
  const float* xb = x + (size_t)b * C_ * N_ + px0 + spx;

  f32x4 acc[9];
  #pragma unroll
  for (int t = 0; t < 9; ++t) acc[t] = (f32x4){0.f, 0.f, 0.f, 0.f};

  float vx[8];
  #pragma unroll
  for (int j = 0; j < 8; ++j) vx[j] = xb[(size_t)(skg * 8 + j) * N_];

  for (int step = 0; step < 8; ++step) {
    const int c0  = step * 32;
    const int buf = step & 1;
    // pack current regs -> LDS
    {
      uint4 u;
      u.x = packbf(vx[0], vx[1]);
      u.y = packbf(vx[2], vx[3]);
      u.z = packbf(vx[4], vx[5]);
      u.w = packbf(vx[6], vx[7]);
      *reinterpret_cast<uint4*>(&s_x[buf][skg * 512 + spx * 8]) = u;
    }
    // issue next step's loads (latency hides under barrier + MFMAs)
    float vn[8];
    if (step < 7) {
      const int c1 = c0 + 32;
      #pragma unroll
      for (int j = 0; j < 8; ++j) vn[j] = xb[(size_t)(c1 + skg * 8 + j) * N_];
    }
    __syncthreads();
    // compute: 9 o-tiles, K=32 per mfma
    const short8b bfrag = *reinterpret_cast<const short8b*>(
        &s_x[buf][lg * 512 + (w * 16 + ln15) * 8]);
    #pragma unroll
    for (int ot = 0; ot < 9; ++ot) {
      const short8b afrag = *reinterpret_cast<const short8b*>(
          wbf + (size_t)(ot * 16 + ln15) * C_ + c0 + lg * 8);
      acc[ot] = __builtin_amdgcn_mfma_f32_16x16x32_bf16(afrag, bfrag, acc[ot], 0, 0, 0);
    }
    if (step < 7) {
      #pragma unroll
      for (int j = 0; j < 8; ++j) vx[j] = vn[j];
    }
  }

  // store: D[row = ot*16 + lg*4 + r][col = px0 + w*16 + ln15]
  float* pb = proj + (size_t)b * OTOT_ * N_ + px0 + w * 16 + ln15;
  #pragma unroll
  for (int ot = 0; ot < 9; ++ot)
    #pragma unroll
    for (int r = 0; r < 4; ++r)
      pb[(size_t)(ot * 16 + lg * 4 + r) * N_] = acc[ot][r];
}

// ---------------------------------------------------------------------------
// K2 v3: GroupNorm stats, float4 loads.
// ---------------------------------------------------------------------------
__global__ __launch_bounds__(256) void k_stats(const float* __restrict__ proj,
    float* __restrict__ meanp, float* __restrict__ rstdp) {
  const int bg = blockIdx.x;           // b*36 + g
  const int b = bg / NG_, g = bg % NG_;
  const float* p = proj + ((size_t)b * OTOT_ + g * 4) * N_;
  float s = 0.f, s2 = 0.f;
  for (int i = threadIdx.x * 4; i < 4 * N_; i += 1024) {
    const float4 v = *reinterpret_cast<const float4*>(p + i);
    s  += v.x + v.y + v.z + v.w;
    s2 += v.x * v.x + v.y * v.y + v.z * v.z + v.w * v.w;
  }
  __shared__ float rs[256], rq[256];
  rs[threadIdx.x] = s; rq[threadIdx.x] = s2;
  __syncthreads();
  for (int off = 128; off > 0; off >>= 1) {
    if (threadIdx.x < off) {
      rs[threadIdx.x] += rs[threadIdx.x + off];
      rq[threadIdx.x] += rq[threadIdx.x + off];
    }
    __syncthreads();
  }
  if (threadIdx.x == 0) {
    float m   = rs[0] * (1.f / 16384.f);
    float var = rq[0] * (1.f / 16384.f) - m * m;
    meanp[bg] = m;
    rstdp[bg] = rsqrtf(var + EPS_);
  }
}

// ---------------------------------------------------------------------------
// K3: k GroupNorm-apply + softmax over n.
// ---------------------------------------------------------------------------
__global__ __launch_bounds__(256) void k_softmax(const float* __restrict__ proj,
    const float* __restrict__ meanp, const float* __restrict__ rstdp,
    const float* __restrict__ gkg, const float* __restrict__ gkb,
    float* __restrict__ ksm) {
  const int bk = blockIdx.x;
  const int b = bk >> 4, kk = bk & 15;
  const int g = 16 + (kk >> 2);
  const float mu = meanp[b * NG_ + g], rs = rstdp[b * NG_ + g];
  const float ga = gkg[kk], be = gkb[kk];
  const float* p = proj + ((size_t)b * OTOT_ + 64 + kk) * N_;
  float* o = ksm + ((size_t)b * KK_ + kk) * N_;

  float xn[16];
  float m = -1e30f;
  #pragma unroll
  for (int i = 0; i < 16; ++i) {
    float v = (p[threadIdx.x + i * 256] - mu) * rs * ga + be;
    xn[i] = v;
    m = fmaxf(m, v);
  }
  __shared__ float red[256];
  red[threadIdx.x] = m; __syncthreads();
  for (int off = 128; off > 0; off >>= 1) {
    if (threadIdx.x < off)
      red[threadIdx.x] = fmaxf(red[threadIdx.x], red[threadIdx.x + off]);
    __syncthreads();
  }
  m = red[0];
  __syncthreads();
  float s = 0.f;
  #pragma unroll
  for (int i = 0; i < 16; ++i) { xn[i] = __expf(xn[i] - m); s += xn[i]; }
  red[threadIdx.x] = s; __syncthreads();
  for (int off = 128; off > 0; off >>= 1) {
    if (threadIdx.x < off) red[threadIdx.x] += red[threadIdx.x + off];
    __syncthreads();
  }
  float inv = 1.f / red[0];
  #pragma unroll
  for (int i = 0; i < 16; ++i) o[threadIdx.x + i * 256] = xn[i] * inv;
}

// ---------------------------------------------------------------------------
// K4 v2: content lambda, float4 loads.
// ---------------------------------------------------------------------------
__global__ __launch_bounds__(256) void k_lam(const float* __restrict__ proj,
    const float* __restrict__ ksm,
    const float* __restrict__ meanp, const float* __restrict__ rstdp,
    const float* __restrict__ gvg, const float* __restrict__ gvb,
    float* __restrict__ lam) {
  const int bv = blockIdx.x;
  const int b = bv >> 6, v = bv & 63;
  const int g = 20 + (v >> 2);
  const float mu = meanp[b * NG_ + g], rs = rstdp[b * NG_ + g];
  const float ga = gvg[v], be = gvb[v];
  const float* pv = proj + ((size_t)b * OTOT_ + 80 + v) * N_;
  const float* pk = ksm + (size_t)b * KK_ * N_;

  float acc[16];
  #pragma unroll
  for (int k = 0; k < 16; ++k) acc[k] = 0.f;
  for (int n = threadIdx.x * 4; n < N_; n += 1024) {
    float4 vn = *reinterpret_cast<const float4*>(pv + n);
    vn.x = (vn.x - mu) * rs * ga + be;
    vn.y = (vn.y - mu) * rs * ga + be;
    vn.z = (vn.z - mu) * rs * ga + be;
    vn.w = (vn.w - mu) * rs * ga + be;
    #pragma unroll
    for (int k = 0; k < 16; ++k) {
      const float4 kv = *reinterpret_cast<const float4*>(pk + (size_t)k * N_ + n);
      acc[k] += kv.x * vn.x + kv.y * vn.y + kv.z * vn.z + kv.w * vn.w;
    }
  }
  __shared__ float red[64];
  const int lane = threadIdx.x & 63, wid = threadIdx.x >> 6;
  #pragma unroll
  for (int k = 0; k < 16; ++k) {
    float s = acc[k];
    #pragma unroll
    for (int off = 32; off > 0; off >>= 1) s += __shfl_down(s, off, 64);
    if (lane == 0) red[wid * 16 + k] = s;
  }
  __syncthreads();
  if (threadIdx.x < 16) {
    float s = red[threadIdx.x] + red[16 + threadIdx.x] +
              red[32 + threadIdx.x] + red[48 + threadIdx.x];
    lam[((size_t)b * KK_ + threadIdx.x) * VV_ + v] = s;
  }
}

// ---------------------------------------------------------------------------
// K-QE: qe[t][n] = sum_k GN(q)[h,k,n]*emb[k,t] once per (b,h,n), bf16 out.
// ---------------------------------------------------------------------------
__global__ __launch_bounds__(256) void k_qe(const float* __restrict__ proj,
    const float* __restrict__ meanp, const float* __restrict__ rstdp,
    const float* __restrict__ gqg, const float* __restrict__ gqb,
    const float* __restrict__ emb, unsigned short* __restrict__ qeb) {
  const int strip = blockIdx.x;   // 16
  const int h     = blockIdx.y;   // 4
  const int b     = blockIdx.z;   // 16
  const int r0    = strip * 4;
  const int tid   = threadIdx.x;
  const int wid   = __builtin_amdgcn_readfirstlane(tid >> 6);  // tap-split
  const int slot  = tid & 63;
  const int ty    = slot >> 4, txg = slot & 15;
  const int x0    = txg << 2;
  const int n0    = (r0 + ty) * W_ + x0;

  const float* pb = proj + (size_t)b * OTOT_ * N_;

  float qn[4][16];
  #pragma unroll
  for (int k = 0; k < 16; ++k) {
    const int o = h * 16 + k, g = o >> 2;
    const float mu = meanp[b * NG_ + g], rs = rstdp[b * NG_ + g];
    const float ga = gqg[o], be = gqb[o];
    const float4 qv = *reinterpret_cast<const float4*>(pb + (size_t)o * N_ + n0);
    qn[0][k] = (qv.x - mu) * rs * ga + be;
    qn[1][k] = (qv.y - mu) * rs * ga + be;
    qn[2][k] = (qv.z - mu) * rs * ga + be;
    qn[3][k] = (qv.w - mu) * rs * ga + be;
  }

  unsigned short* qb = qeb + (size_t)(b * 4 + h) * 49 * N_;
  const int t0 = wid * 13;
  const int t1 = (t0 + 13 < 49) ? (t0 + 13) : 49;
  for (int t = t0; t < t1; ++t) {
    float p0 = 0.f, p1 = 0.f, p2 = 0.f, p3 = 0.f;
    #pragma unroll
    for (int k = 0; k < 16; ++k) {
      const float e = emb[k * 49 + t];   // uniform -> scalar
      p0 += qn[0][k] * e; p1 += qn[1][k] * e;
      p2 += qn[2][k] * e; p3 += qn[3][k] * e;
    }
    uint2 pk;
    pk.x = packbf(p0, p1);
    pk.y = packbf(p2, p3);
    *reinterpret_cast<uint2*>(&qb[(size_t)t * N_ + n0]) = pk;
  }
}

// ---------------------------------------------------------------------------
// K5 v11: conv+combine, vsplit=16 (4 v-channels per block). LDS ~30.5 KB ->
// 5 blocks/CU (20 waves). Grid 16384, XCD-chunked. Same proven phases.
// ---------------------------------------------------------------------------
__global__ __launch_bounds__(256) void k_final_v11(const float* __restrict__ proj,
    const float* __restrict__ meanp, const float* __restrict__ rstdp,
    const float* __restrict__ gqg, const float* __restrict__ gqb,
    const float* __restrict__ gvg, const float* __restrict__ gvb,
    const unsigned short* __restrict__ qeb, const float* __restrict__ lam,
    float* __restrict__ out) {
  const int wgid = (blockIdx.x & 7) * 2048 + (blockIdx.x >> 3);
  const int b     = wgid >> 10;         // 0..15
  const int r2    = wgid & 1023;
  const int h     = r2 & 3;
  const int strip = (r2 >> 2) & 15;
  const int s     = r2 >> 6;            // v-set 0..15 (4 channels each)

  const int r0    = strip * 4;
  const int tid   = threadIdx.x;
  const int vlane = __builtin_amdgcn_readfirstlane(tid >> 6);
  const int slot  = tid & 63;
  const int ty    = slot >> 4;
  const int txg   = slot & 15;
  const int x0    = txg << 2;
  const int n0    = (r0 + ty) * W_ + x0;
  const int pos4  = ty * 64 + x0;

  __shared__ unsigned short s_qe[49 * 256];   // bf16 qe[t][pos], 24.5 KB
  __shared__ unsigned short s_v[4 * 720];     // bf16 v[ch][10][72], 5.6 KB
  __shared__ float s_mu[NG_], s_rs[NG_];
  __shared__ float s_gvw[64], s_gvb[64];

  // phase 0: constants + zero the 2 pad columns of s_v
  if (tid < NG_) { s_mu[tid] = meanp[b * NG_ + tid]; s_rs[tid] = rstdp[b * NG_ + tid]; }
  else if (tid >= 64 && tid < 128) { s_gvw[tid - 64] = gvg[tid - 64]; s_gvb[tid - 64] = gvb[tid - 64]; }
  if (tid < 80) {
    const int vh = tid / 20, rem = tid % 20;
    const int ry = rem >> 1, side = rem & 1;
    uint2 z; z.x = 0u; z.y = 0u;
    *reinterpret_cast<uint2*>(&s_v[vh * 720 + ry * 72 + side * 68]) = z;
  }
  __syncthreads();

  const float* pb = proj + (size_t)b * OTOT_ * N_;

  // phase 1a: bulk-prefetch qe tile (49 taps x 256 px) into s_qe, coalesced.
  {
    const unsigned short* qb = qeb + (size_t)(b * 4 + h) * 49 * N_ + r0 * 64;
    for (int i = tid; i < 1568; i += 256) {
      const int t = i >> 5;          // tap
      const int r = i & 31;          // 16B chunk within the 512B tap row
      const uint4 d = *reinterpret_cast<const uint4*>(&qb[(size_t)t * N_ + r * 8]);
      *reinterpret_cast<uint4*>(&s_qe[t * 256 + r * 8]) = d;
    }
  }

  // phase 1b: stage this block's 4-ch v-set. Thread = (ch4, rowgrp4, rx4);
  // each thread does rows rg, rg+4, rg+8 (guard <10). Division-free.
  {
    const int vh  = (tid >> 6) & 3;      // 0..3
    const int rg  = (tid >> 4) & 3;      // 0..3
    const int rx4 = (tid & 15) + 1;      // 1..16
    const int gx0 = (rx4 << 2) - 4;
    const int v   = s * 4 + vh;
    const int g   = 20 + (v >> 2);
    const float mu = s_mu[g], rs = s_rs[g], ga = s_gvw[v], be = s_gvb[v];
    const float* src = pb + (size_t)(80 + v) * N_ + gx0;
    unsigned short* dst = &s_v[vh * 720 + (rx4 << 2)];
    #pragma unroll
    for (int rr = 0; rr < 3; ++rr) {
      const int ry = rg + 4 * rr;
      if (ry < 10) {
        const int gy = r0 - 3 + ry;
        float4 f = make_float4(0.f, 0.f, 0.f, 0.f);
        if (gy >= 0 && gy < H_) {
          f = *reinterpret_cast<const float4*>(src + (size_t)gy * W_);
          f.x = (f.x - mu) * rs * ga + be;
          f.y = (f.y - mu) * rs * ga + be;
          f.z = (f.z - mu) * rs * ga + be;
          f.w = (f.w - mu) * rs * ga + be;
        }
        uint2 w;
        w.x = packbf(f.x, f.y);
        w.y = packbf(f.z, f.w);
        *reinterpret_cast<uint2*>(dst + ry * 72) = w;
      }
    }
  }
  __syncthreads();   // the one hot barrier

  // phase 2: content (k-outer, GN on the fly, scalar lam) + conv (all-LDS)
  float acc[4];
  #pragma unroll
  for (int p = 0; p < 4; ++p) acc[p] = 0.f;

  const float* lb = lam + (size_t)b * 1024;
  const int v_out = __builtin_amdgcn_readfirstlane(s * 4 + vlane);
  #pragma unroll
  for (int k = 0; k < 16; ++k) {
    const int o = h * 16 + k, g = o >> 2;
    const float mu = s_mu[g], rs = s_rs[g];
    const float ga = gqg[o], be = gqb[o];   // uniform -> scalar
    const float4 qv = *reinterpret_cast<const float4*>(pb + (size_t)o * N_ + n0);
    const float lv = lb[k * 64 + v_out];    // uniform -> scalar
    acc[0] += ((qv.x - mu) * rs * ga + be) * lv;
    acc[1] += ((qv.y - mu) * rs * ga + be) * lv;
    acc[2] += ((qv.z - mu) * rs * ga + be) * lv;
    acc[3] += ((qv.w - mu) * rs * ga + be) * lv;
  }

  #pragma unroll
  for (int i = 0; i < 7; ++i) {
    float qeu[7][4];
    #pragma unroll
    for (int j = 0; j < 7; ++j) {
      const uint2 pk = *reinterpret_cast<const uint2*>(&s_qe[(i * 7 + j) * 256 + pos4]);
      qeu[j][0] = bflo(pk.x); qeu[j][1] = bfhi(pk.x);
      qeu[j][2] = bflo(pk.y); qeu[j][3] = bfhi(pk.y);
    }
    {
      const unsigned short* sv = &s_v[vlane * 720 + (ty + i) * 72 + x0];
      const uint2 wa = *reinterpret_cast<const uint2*>(sv);
      const uint2 wb = *reinterpret_cast<const uint2*>(sv + 4);
      const uint2 wc = *reinterpret_cast<const uint2*>(sv + 8);
      float wv[12];
      wv[0] = bflo(wa.x); wv[1] = bfhi(wa.x); wv[2]  = bflo(wa.y); wv[3]  = bfhi(wa.y);
      wv[4] = bflo(wb.x); wv[5] = bfhi(wb.x); wv[6]  = bflo(wb.y); wv[7]  = bfhi(wb.y);
      wv[8] = bflo(wc.x); wv[9] = bfhi(wc.x); wv[10] = bflo(wc.y); wv[11] = bfhi(wc.y);
      #pragma unroll
      for (int j = 0; j < 7; ++j)
        #pragma unroll
        for (int p = 0; p < 4; ++p)
          acc[p] += qeu[j][p] * wv[p + j + 1];
    }
  }

  {
    const int v = s * 4 + vlane;
    float4 o4 = make_float4(acc[0], acc[1], acc[2], acc[3]);
    *reinterpret_cast<float4*>(out + ((size_t)b * 256 + h * 64 + v) * N_ + n0) = o4;
  }
}

// ---------------------------------------------------------------------------
extern "C" void kernel_launch(void* const* d_in, const int* in_sizes, int n_in,
                              void* d_out, int out_size, void* d_ws, size_t ws_size,
                              hipStream_t stream) {
  const float* x   = (const float*)d_in[0];
  const float* wq  = (const float*)d_in[1];
  const float* gqg = (const float*)d_in[2];
  const float* gqb = (const float*)d_in[3];
  const float* wk  = (const float*)d_in[4];
  const float* gkg = (const float*)d_in[5];
  const float* gkb = (const float*)d_in[6];
  const float* wv  = (const float*)d_in[7];
  const float* gvg = (const float*)d_in[8];
  const float* gvb = (const float*)d_in[9];
  const float* emb = (const float*)d_in[10];
  float* out = (float*)d_out;
  float* ws  = (float*)d_ws;

  float* proj  = ws;                                    // B*144*N floats
  float* meanp = proj + (size_t)B_ * OTOT_ * N_;        // B*36
  float* rstdp = meanp + B_ * NG_;                      // B*36
  float* ksm   = rstdp + B_ * NG_;                      // B*16*N
  float* lam   = ksm + (size_t)B_ * KK_ * N_;           // B*16*64
  unsigned short* qeb = (unsigned short*)(lam + (size_t)B_ * KK_ * VV_);
  unsigned short* wbf = qeb + (size_t)B_ * HEADS_ * 49 * N_;

  k_wcvt<<<dim3(144), 256, 0, stream>>>(wq, wk, wv, wbf);
  k_proj_mfma<<<dim3(64, B_), 256, 0, stream>>>(x, wbf, proj);
  k_stats<<<dim3(B_ * NG_), 256, 0, stream>>>(proj, meanp, rstdp);
  k_softmax<<<dim3(B_ * KK_), 256, 0, stream>>>(proj, meanp, rstdp, gkg, gkb, ksm);
  k_lam<<<dim3(B_ * VV_), 256, 0, stream>>>(proj, ksm, meanp, rstdp, gvg, gvb, lam);
  k_qe<<<dim3(16, HEADS_, B_), 256, 0, stream>>>(proj, meanp, rstdp, gqg, gqb, emb, qeb);
  k_final_v11<<<dim3(16384), 256, 0, stream>>>(proj, meanp, rstdp,
      gqg, gqb, gvg, gvb, qeb, lam, out);
}

// Round 19
// 175.613 us; speedup vs baseline: 1.1196x; 1.1196x over previous
//
#include <hip/hip_runtime.h>
#include <math.h>

#define B_    16
#define C_    256
#define H_    64
#define W_    64
#define N_    4096
#define HEADS_ 4
#define KK_   16
#define VV_   64
#define M_    7
#define PAD_  3
#define OTOT_ 144   // 64 q + 16 k + 64 v channels
#define NG_   36    // 36 groups of 4 channels
#define EPS_  1e-5f

typedef __attribute__((ext_vector_type(8))) short short8b;
typedef __attribute__((ext_vector_type(4))) float f32x4;

// bf16 helpers (round-half-up; error ~2^-9 relative, fine vs threshold)
__device__ inline unsigned packbf(float a, float b) {
  unsigned ua = __float_as_uint(a) + 0x8000u;
  unsigned ub = __float_as_uint(b) + 0x8000u;
  return (ua >> 16) | (ub & 0xffff0000u);
}
__device__ inline float bflo(unsigned u) { return __uint_as_float(u << 16); }
__device__ inline float bfhi(unsigned u) { return __uint_as_float(u & 0xffff0000u); }

// ---------------------------------------------------------------------------
// K0: convert wq/wk/wv -> bf16 wbf[144][256] (row-major o-major).
// ---------------------------------------------------------------------------
__global__ __launch_bounds__(256) void k_wcvt(const float* __restrict__ wq,
    const float* __restrict__ wk, const float* __restrict__ wv,
    unsigned short* __restrict__ wbf) {
  const int idx = blockIdx.x * 256 + threadIdx.x;   // grid 144 -> 36864
  if (idx >= OTOT_ * C_) return;
  const int o = idx >> 8, c = idx & 255;
  const float* wrow = (o < 64) ? (wq + o * C_)
                     : ((o < 80) ? (wk + (o - 64) * C_) : (wv + (o - 80) * C_));
  wbf[idx] = (unsigned short)((__float_as_uint(wrow[c]) + 0x8000u) >> 16);
}

// ---------------------------------------------------------------------------
// K1 v7 (R17/R18 proven): MFMA projection GEMM, register-prefetch pipeline.
// ---------------------------------------------------------------------------
__global__ __launch_bounds__(256) void k_proj_mfma(const float* __restrict__ x,
    const unsigned short* __restrict__ wbf, float* __restrict__ proj) {
  const int pt = blockIdx.x;       // 0..63 px-tile (64 px)
  const int b  = blockIdx.y;
  const int px0 = pt * 64;
  const int tid = threadIdx.x;
  const int w    = tid >> 6;       // wave id
  const int lane = tid & 63;
  const int ln15 = lane & 15;
  const int lg   = lane >> 4;      // k-group 0..3

  __shared__ unsigned short s_x[2][2048];   // [buf][kg*512 + px*8]

  const int spx = tid & 63;
  const int skg = tid >> 6;
  const float* xb = x + (size_t)b * C_ * N_ + px0 + spx;

  f32x4 acc[9];
  #pragma unroll
  for (int t = 0; t < 9; ++t) acc[t] = (f32x4){0.f, 0.f, 0.f, 0.f};

  float vx[8];
  #pragma unroll
  for (int j = 0; j < 8; ++j) vx[j] = xb[(size_t)(skg * 8 + j) * N_];

  for (int step = 0; step < 8; ++step) {
    const int c0  = step * 32;
    const int buf = step & 1;
    {
      uint4 u;
      u.x = packbf(vx[0], vx[1]);
      u.y = packbf(vx[2], vx[3]);
      u.z = packbf(vx[4], vx[5]);
      u.w = packbf(vx[6], vx[7]);
      *reinterpret_cast<uint4*>(&s_x[buf][skg * 512 + spx * 8]) = u;
    }
    float vn[8];
    if (step < 7) {
      const int c1 = c0 + 32;
      #pragma unroll
      for (int j = 0; j < 8; ++j) vn[j] = xb[(size_t)(c1 + skg * 8 + j) * N_];
    }
    __syncthreads();
    const short8b bfrag = *reinterpret_cast<const short8b*>(
        &s_x[buf][lg * 512 + (w * 16 + ln15) * 8]);
    #pragma unroll
    for (int ot = 0; ot < 9; ++ot) {
      const short8b afrag = *reinterpret_cast<const short8b*>(
          wbf + (size_t)(ot * 16 + ln15) * C_ + c0 + lg * 8);
      acc[ot] = __builtin_amdgcn_mfma_f32_16x16x32_bf16(afrag, bfrag, acc[ot], 0, 0, 0);
    }
    if (step < 7) {
      #pragma unroll
      for (int j = 0; j < 8; ++j) vx[j] = vn[j];
    }
  }

  float* pb = proj + (size_t)b * OTOT_ * N_ + px0 + w * 16 + ln15;
  #pragma unroll
  for (int ot = 0; ot < 9; ++ot)
    #pragma unroll
    for (int r = 0; r < 4; ++r)
      pb[(size_t)(ot * 16 + lg * 4 + r) * N_] = acc[ot][r];
}

// ---------------------------------------------------------------------------
// K2 v3: GroupNorm stats, float4 loads.
// ---------------------------------------------------------------------------
__global__ __launch_bounds__(256) void k_stats(const float* __restrict__ proj,
    float* __restrict__ meanp, float* __restrict__ rstdp) {
  const int bg = blockIdx.x;           // b*36 + g
  const int b = bg / NG_, g = bg % NG_;
  const float* p = proj + ((size_t)b * OTOT_ + g * 4) * N_;
  float s = 0.f, s2 = 0.f;
  for (int i = threadIdx.x * 4; i < 4 * N_; i += 1024) {
    const float4 v = *reinterpret_cast<const float4*>(p + i);
    s  += v.x + v.y + v.z + v.w;
    s2 += v.x * v.x + v.y * v.y + v.z * v.z + v.w * v.w;
  }
  __shared__ float rs[256], rq[256];
  rs[threadIdx.x] = s; rq[threadIdx.x] = s2;
  __syncthreads();
  for (int off = 128; off > 0; off >>= 1) {
    if (threadIdx.x < off) {
      rs[threadIdx.x] += rs[threadIdx.x + off];
      rq[threadIdx.x] += rq[threadIdx.x + off];
    }
    __syncthreads();
  }
  if (threadIdx.x == 0) {
    float m   = rs[0] * (1.f / 16384.f);
    float var = rq[0] * (1.f / 16384.f) - m * m;
    meanp[bg] = m;
    rstdp[bg] = rsqrtf(var + EPS_);
  }
}

// ---------------------------------------------------------------------------
// K3: k GroupNorm-apply + softmax over n.
// ---------------------------------------------------------------------------
__global__ __launch_bounds__(256) void k_softmax(const float* __restrict__ proj,
    const float* __restrict__ meanp, const float* __restrict__ rstdp,
    const float* __restrict__ gkg, const float* __restrict__ gkb,
    float* __restrict__ ksm) {
  const int bk = blockIdx.x;
  const int b = bk >> 4, kk = bk & 15;
  const int g = 16 + (kk >> 2);
  const float mu = meanp[b * NG_ + g], rs = rstdp[b * NG_ + g];
  const float ga = gkg[kk], be = gkb[kk];
  const float* p = proj + ((size_t)b * OTOT_ + 64 + kk) * N_;
  float* o = ksm + ((size_t)b * KK_ + kk) * N_;

  float xn[16];
  float m = -1e30f;
  #pragma unroll
  for (int i = 0; i < 16; ++i) {
    float v = (p[threadIdx.x + i * 256] - mu) * rs * ga + be;
    xn[i] = v;
    m = fmaxf(m, v);
  }
  __shared__ float red[256];
  red[threadIdx.x] = m; __syncthreads();
  for (int off = 128; off > 0; off >>= 1) {
    if (threadIdx.x < off)
      red[threadIdx.x] = fmaxf(red[threadIdx.x], red[threadIdx.x + off]);
    __syncthreads();
  }
  m = red[0];
  __syncthreads();
  float s = 0.f;
  #pragma unroll
  for (int i = 0; i < 16; ++i) { xn[i] = __expf(xn[i] - m); s += xn[i]; }
  red[threadIdx.x] = s; __syncthreads();
  for (int off = 128; off > 0; off >>= 1) {
    if (threadIdx.x < off) red[threadIdx.x] += red[threadIdx.x + off];
    __syncthreads();
  }
  float inv = 1.f / red[0];
  #pragma unroll
  for (int i = 0; i < 16; ++i) o[threadIdx.x + i * 256] = xn[i] * inv;
}

// ---------------------------------------------------------------------------
// K4 v2: content lambda, float4 loads.
// ---------------------------------------------------------------------------
__global__ __launch_bounds__(256) void k_lam(const float* __restrict__ proj,
    const float* __restrict__ ksm,
    const float* __restrict__ meanp, const float* __restrict__ rstdp,
    const float* __restrict__ gvg, const float* __restrict__ gvb,
    float* __restrict__ lam) {
  const int bv = blockIdx.x;
  const int b = bv >> 6, v = bv & 63;
  const int g = 20 + (v >> 2);
  const float mu = meanp[b * NG_ + g], rs = rstdp[b * NG_ + g];
  const float ga = gvg[v], be = gvb[v];
  const float* pv = proj + ((size_t)b * OTOT_ + 80 + v) * N_;
  const float* pk = ksm + (size_t)b * KK_ * N_;

  float acc[16];
  #pragma unroll
  for (int k = 0; k < 16; ++k) acc[k] = 0.f;
  for (int n = threadIdx.x * 4; n < N_; n += 1024) {
    float4 vn = *reinterpret_cast<const float4*>(pv + n);
    vn.x = (vn.x - mu) * rs * ga + be;
    vn.y = (vn.y - mu) * rs * ga + be;
    vn.z = (vn.z - mu) * rs * ga + be;
    vn.w = (vn.w - mu) * rs * ga + be;
    #pragma unroll
    for (int k = 0; k < 16; ++k) {
      const float4 kv = *reinterpret_cast<const float4*>(pk + (size_t)k * N_ + n);
      acc[k] += kv.x * vn.x + kv.y * vn.y + kv.z * vn.z + kv.w * vn.w;
    }
  }
  __shared__ float red[64];
  const int lane = threadIdx.x & 63, wid = threadIdx.x >> 6;
  #pragma unroll
  for (int k = 0; k < 16; ++k) {
    float s = acc[k];
    #pragma unroll
    for (int off = 32; off > 0; off >>= 1) s += __shfl_down(s, off, 64);
    if (lane == 0) red[wid * 16 + k] = s;
  }
  __syncthreads();
  if (threadIdx.x < 16) {
    float s = red[threadIdx.x] + red[16 + threadIdx.x] +
              red[32 + threadIdx.x] + red[48 + threadIdx.x];
    lam[((size_t)b * KK_ + threadIdx.x) * VV_ + v] = s;
  }
}

// ---------------------------------------------------------------------------
// K-QE: qe[t][n] = sum_k GN(q)[h,k,n]*emb[k,t] once per (b,h,n), bf16 out.
// ---------------------------------------------------------------------------
__global__ __launch_bounds__(256) void k_qe(const float* __restrict__ proj,
    const float* __restrict__ meanp, const float* __restrict__ rstdp,
    const float* __restrict__ gqg, const float* __restrict__ gqb,
    const float* __restrict__ emb, unsigned short* __restrict__ qeb) {
  const int strip = blockIdx.x;   // 16
  const int h     = blockIdx.y;   // 4
  const int b     = blockIdx.z;   // 16
  const int r0    = strip * 4;
  const int tid   = threadIdx.x;
  const int wid   = __builtin_amdgcn_readfirstlane(tid >> 6);  // tap-split
  const int slot  = tid & 63;
  const int ty    = slot >> 4, txg = slot & 15;
  const int x0    = txg << 2;
  const int n0    = (r0 + ty) * W_ + x0;

  const float* pb = proj + (size_t)b * OTOT_ * N_;

  float qn[4][16];
  #pragma unroll
  for (int k = 0; k < 16; ++k) {
    const int o = h * 16 + k, g = o >> 2;
    const float mu = meanp[b * NG_ + g], rs = rstdp[b * NG_ + g];
    const float ga = gqg[o], be = gqb[o];
    const float4 qv = *reinterpret_cast<const float4*>(pb + (size_t)o * N_ + n0);
    qn[0][k] = (qv.x - mu) * rs * ga + be;
    qn[1][k] = (qv.y - mu) * rs * ga + be;
    qn[2][k] = (qv.z - mu) * rs * ga + be;
    qn[3][k] = (qv.w - mu) * rs * ga + be;
  }

  unsigned short* qb = qeb + (size_t)(b * 4 + h) * 49 * N_;
  const int t0 = wid * 13;
  const int t1 = (t0 + 13 < 49) ? (t0 + 13) : 49;
  for (int t = t0; t < t1; ++t) {
    float p0 = 0.f, p1 = 0.f, p2 = 0.f, p3 = 0.f;
    #pragma unroll
    for (int k = 0; k < 16; ++k) {
      const float e = emb[k * 49 + t];   // uniform -> scalar
      p0 += qn[0][k] * e; p1 += qn[1][k] * e;
      p2 += qn[2][k] * e; p3 += qn[3][k] * e;
    }
    uint2 pk;
    pk.x = packbf(p0, p1);
    pk.y = packbf(p2, p3);
    *reinterpret_cast<uint2*>(&qb[(size_t)t * N_ + n0]) = pk;
  }
}

// ---------------------------------------------------------------------------
// K5 v10b: R17's proven v10 (vsplit=8), with the content phase HOISTED
// before the hot barrier (its 16 q-loads are independent of the phase-1
// LDS writes, so their latency overlaps the staging drain). Conv after the
// barrier is pure LDS+FMA. No register-held staging arrays (v9's mistake).
// ---------------------------------------------------------------------------
__global__ __launch_bounds__(256) void k_final_v10b(const float* __restrict__ proj,
    const float* __restrict__ meanp, const float* __restrict__ rstdp,
    const float* __restrict__ gqg, const float* __restrict__ gqb,
    const float* __restrict__ gvg, const float* __restrict__ gvb,
    const unsigned short* __restrict__ qeb, const float* __restrict__ lam,
    float* __restrict__ out) {
  const int wgid = (blockIdx.x & 7) * 1024 + (blockIdx.x >> 3);
  const int b     = wgid >> 9;          // 0..15
  const int r2    = wgid & 511;
  const int h     = r2 & 3;
  const int strip = (r2 >> 2) & 15;
  const int s     = r2 >> 6;            // v-set 0..7 (8 channels each)

  const int r0    = strip * 4;
  const int tid   = threadIdx.x;
  const int vlane = __builtin_amdgcn_readfirstlane(tid >> 6);
  const int slot  = tid & 63;
  const int ty    = slot >> 4;
  const int txg   = slot & 15;
  const int x0    = txg << 2;
  const int n0    = (r0 + ty) * W_ + x0;
  const int pos4  = ty * 64 + x0;

  __shared__ unsigned short s_qe[49 * 256];   // bf16 qe[t][pos], 24.5 KB
  __shared__ unsigned short s_v[8 * 720];     // bf16 v[ch][10][72], 11.25 KB
  __shared__ float s_mu[NG_], s_rs[NG_];
  __shared__ float s_gvw[64], s_gvb[64];

  // phase 0: constants + zero the 2 pad columns of s_v
  if (tid < NG_) { s_mu[tid] = meanp[b * NG_ + tid]; s_rs[tid] = rstdp[b * NG_ + tid]; }
  else if (tid >= 64 && tid < 128) { s_gvw[tid - 64] = gvg[tid - 64]; s_gvb[tid - 64] = gvb[tid - 64]; }
  for (int i = tid; i < 160; i += 256) {
    const int vh = i / 20, rem = i % 20;
    const int ry = rem >> 1, side = rem & 1;
    uint2 z; z.x = 0u; z.y = 0u;
    *reinterpret_cast<uint2*>(&s_v[vh * 720 + ry * 72 + side * 68]) = z;
  }
  __syncthreads();

  const float* pb = proj + (size_t)b * OTOT_ * N_;

  // phase 1a: bulk-prefetch qe tile (49 taps x 256 px) into s_qe, coalesced.
  {
    const unsigned short* qb = qeb + (size_t)(b * 4 + h) * 49 * N_ + r0 * 64;
    for (int i = tid; i < 1568; i += 256) {
      const int t = i >> 5;          // tap
      const int r = i & 31;          // 16B chunk within the 512B tap row
      const uint4 d = *reinterpret_cast<const uint4*>(&qb[(size_t)t * N_ + r * 8]);
      *reinterpret_cast<uint4*>(&s_qe[t * 256 + r * 8]) = d;
    }
  }

  // phase 1b: stage this block's 8-ch v-set. Thread = (half, ch8, rx4);
  // each thread does 5 rows. Division-free.
  {
    const int half = tid >> 7;           // 0..1 -> rows 0-4 / 5-9
    const int vh   = (tid >> 4) & 7;     // 0..7
    const int rx4  = (tid & 15) + 1;     // 1..16
    const int gx0  = (rx4 << 2) - 4;
    const int v    = s * 8 + vh;
    const int g    = 20 + (v >> 2);
    const float mu = s_mu[g], rs = s_rs[g], ga = s_gvw[v], be = s_gvb[v];
    const float* src = pb + (size_t)(80 + v) * N_ + gx0;
    unsigned short* dst = &s_v[vh * 720 + (rx4 << 2)];
    #pragma unroll
    for (int rr = 0; rr < 5; ++rr) {
      const int ry = half * 5 + rr;
      const int gy = r0 - 3 + ry;
      float4 f = make_float4(0.f, 0.f, 0.f, 0.f);
      if (gy >= 0 && gy < H_) {
        f = *reinterpret_cast<const float4*>(src + (size_t)gy * W_);
        f.x = (f.x - mu) * rs * ga + be;
        f.y = (f.y - mu) * rs * ga + be;
        f.z = (f.z - mu) * rs * ga + be;
        f.w = (f.w - mu) * rs * ga + be;
      }
      uint2 w;
      w.x = packbf(f.x, f.y);
      w.y = packbf(f.z, f.w);
      *reinterpret_cast<uint2*>(dst + ry * 72) = w;
    }
  }

  // phase 1c (hoisted content): independent of phase-1 LDS writes; the 16
  // q-load latencies overlap the staging drain instead of the conv.
  float acc[2][4];
  #pragma unroll
  for (int vj = 0; vj < 2; ++vj)
    #pragma unroll
    for (int p = 0; p < 4; ++p) acc[vj][p] = 0.f;

  const float* lb = lam + (size_t)b * 1024;
  #pragma unroll
  for (int k = 0; k < 16; ++k) {
    const int o = h * 16 + k, g = o >> 2;
    const float mu = s_mu[g], rs = s_rs[g];
    const float ga = gqg[o], be = gqb[o];   // uniform -> scalar
    const float4 qv = *reinterpret_cast<const float4*>(pb + (size_t)o * N_ + n0);
    const float q0 = (qv.x - mu) * rs * ga + be;
    const float q1 = (qv.y - mu) * rs * ga + be;
    const float q2 = (qv.z - mu) * rs * ga + be;
    const float q3 = (qv.w - mu) * rs * ga + be;
    #pragma unroll
    for (int vj = 0; vj < 2; ++vj) {
      const int v = __builtin_amdgcn_readfirstlane(s * 8 + vj * 4 + vlane);
      const float lv = lb[k * 64 + v];      // uniform -> scalar
      acc[vj][0] += q0 * lv; acc[vj][1] += q1 * lv;
      acc[vj][2] += q2 * lv; acc[vj][3] += q3 * lv;
    }
  }
  __syncthreads();   // the one hot barrier

  // phase 2: conv = pure LDS + FMA
  #pragma unroll
  for (int i = 0; i < 7; ++i) {
    float qeu[7][4];
    #pragma unroll
    for (int j = 0; j < 7; ++j) {
      const uint2 pk = *reinterpret_cast<const uint2*>(&s_qe[(i * 7 + j) * 256 + pos4]);
      qeu[j][0] = bflo(pk.x); qeu[j][1] = bfhi(pk.x);
      qeu[j][2] = bflo(pk.y); qeu[j][3] = bfhi(pk.y);
    }
    #pragma unroll
    for (int vj = 0; vj < 2; ++vj) {
      const int vh = vj * 4 + vlane;
      const unsigned short* sv = &s_v[vh * 720 + (ty + i) * 72 + x0];
      const uint2 wa = *reinterpret_cast<const uint2*>(sv);
      const uint2 wb = *reinterpret_cast<const uint2*>(sv + 4);
      const uint2 wc = *reinterpret_cast<const uint2*>(sv + 8);
      float wv[12];
      wv[0] = bflo(wa.x); wv[1] = bfhi(wa.x); wv[2]  = bflo(wa.y); wv[3]  = bfhi(wa.y);
      wv[4] = bflo(wb.x); wv[5] = bfhi(wb.x); wv[6]  = bflo(wb.y); wv[7]  = bfhi(wb.y);
      wv[8] = bflo(wc.x); wv[9] = bfhi(wc.x); wv[10] = bflo(wc.y); wv[11] = bfhi(wc.y);
      #pragma unroll
      for (int j = 0; j < 7; ++j)
        #pragma unroll
        for (int p = 0; p < 4; ++p)
          acc[vj][p] += qeu[j][p] * wv[p + j + 1];
    }
  }

  #pragma unroll
  for (int vj = 0; vj < 2; ++vj) {
    const int v = s * 8 + vj * 4 + vlane;
    float4 o4 = make_float4(acc[vj][0], acc[vj][1], acc[vj][2], acc[vj][3]);
    *reinterpret_cast<float4*>(out + ((size_t)b * 256 + h * 64 + v) * N_ + n0) = o4;
  }
}

// ---------------------------------------------------------------------------
extern "C" void kernel_launch(void* const* d_in, const int* in_sizes, int n_in,
                              void* d_out, int out_size, void* d_ws, size_t ws_size,
                              hipStream_t stream) {
  const float* x   = (const float*)d_in[0];
  const float* wq  = (const float*)d_in[1];
  const float* gqg = (const float*)d_in[2];
  const float* gqb = (const float*)d_in[3];
  const float* wk  = (const float*)d_in[4];
  const float* gkg = (const float*)d_in[5];
  const float* gkb = (const float*)d_in[6];
  const float* wv  = (const float*)d_in[7];
  const float* gvg = (const float*)d_in[8];
  const float* gvb = (const float*)d_in[9];
  const float* emb = (const float*)d_in[10];
  float* out = (float*)d_out;
  float* ws  = (float*)d_ws;

  float* proj  = ws;                                    // B*144*N floats
  float* meanp = proj + (size_t)B_ * OTOT_ * N_;        // B*36
  float* rstdp = meanp + B_ * NG_;                      // B*36
  float* ksm   = rstdp + B_ * NG_;                      // B*16*N
  float* lam   = ksm + (size_t)B_ * KK_ * N_;           // B*16*64
  unsigned short* qeb = (unsigned short*)(lam + (size_t)B_ * KK_ * VV_);
  unsigned short* wbf = qeb + (size_t)B_ * HEADS_ * 49 * N_;

  k_wcvt<<<dim3(144), 256, 0, stream>>>(wq, wk, wv, wbf);
  k_proj_mfma<<<dim3(64, B_), 256, 0, stream>>>(x, wbf, proj);
  k_stats<<<dim3(B_ * NG_), 256, 0, stream>>>(proj, meanp, rstdp);
  k_softmax<<<dim3(B_ * KK_), 256, 0, stream>>>(proj, meanp, rstdp, gkg, gkb, ksm);
  k_lam<<<dim3(B_ * VV_), 256, 0, stream>>>(proj, ksm, meanp, rstdp, gvg, gvb, lam);
  k_qe<<<dim3(16, HEADS_, B_), 256, 0, stream>>>(proj, meanp, rstdp, gqg, gqb, emb, qeb);
  k_final_v10b<<<dim3(8192), 256, 0, stream>>>(proj, meanp, rstdp,
      gqg, gqb, gvg, gvb, qeb, lam, out);
}

// Round 20
// 170.609 us; speedup vs baseline: 1.1524x; 1.0293x over previous
//
#include <hip/hip_runtime.h>
#include <math.h>

#define B_    16
#define C_    256
#define H_    64
#define W_    64
#define N_    4096
#define HEADS_ 4
#define KK_   16
#define VV_   64
#define M_    7
#define PAD_  3
#define OTOT_ 144   // 64 q + 16 k + 64 v channels
#define NG_   36    // 36 groups of 4 channels
#define EPS_  1e-5f

typedef __attribute__((ext_vector_type(8))) short short8b;
typedef __attribute__((ext_vector_type(4))) float f32x4;

// bf16 helpers (round-half-up; error ~2^-9 relative, fine vs threshold)
__device__ inline unsigned packbf(float a, float b) {
  unsigned ua = __float_as_uint(a) + 0x8000u;
  unsigned ub = __float_as_uint(b) + 0x8000u;
  return (ua >> 16) | (ub & 0xffff0000u);
}
__device__ inline float bflo(unsigned u) { return __uint_as_float(u << 16); }
__device__ inline float bfhi(unsigned u) { return __uint_as_float(u & 0xffff0000u); }

// ---------------------------------------------------------------------------
// K0: convert wq/wk/wv -> bf16 wbf[144][256] (row-major o-major).
// ---------------------------------------------------------------------------
__global__ __launch_bounds__(256) void k_wcvt(const float* __restrict__ wq,
    const float* __restrict__ wk, const float* __restrict__ wv,
    unsigned short* __restrict__ wbf) {
  const int idx = blockIdx.x * 256 + threadIdx.x;   // grid 144 -> 36864
  if (idx >= OTOT_ * C_) return;
  const int o = idx >> 8, c = idx & 255;
  const float* wrow = (o < 64) ? (wq + o * C_)
                     : ((o < 80) ? (wk + (o - 64) * C_) : (wv + (o - 80) * C_));
  wbf[idx] = (unsigned short)((__float_as_uint(wrow[c]) + 0x8000u) >> 16);
}

// ---------------------------------------------------------------------------
// K1 v7 (R17 proven): MFMA projection GEMM, register-prefetch pipeline.
// proj[b,o,n] = sum_c W[o,c]*x[b,c,n], bf16 in / fp32 accum.
// ---------------------------------------------------------------------------
__global__ __launch_bounds__(256) void k_proj_mfma(const float* __restrict__ x,
    const unsigned short* __restrict__ wbf, float* __restrict__ proj) {
  const int pt = blockIdx.x;       // 0..63 px-tile (64 px)
  const int b  = blockIdx.y;
  const int px0 = pt * 64;
  const int tid = threadIdx.x;
  const int w    = tid >> 6;       // wave id
  const int lane = tid & 63;
  const int ln15 = lane & 15;
  const int lg   = lane >> 4;      // k-group 0..3

  __shared__ unsigned short s_x[2][2048];   // [buf][kg*512 + px*8]

  const int spx = tid & 63;
  const int skg = tid >> 6;
  const float* xb = x + (size_t)b * C_ * N_ + px0 + spx;

  f32x4 acc[9];
  #pragma unroll
  for (int t = 0; t < 9; ++t) acc[t] = (f32x4){0.f, 0.f, 0.f, 0.f};

  float vx[8];
  #pragma unroll
  for (int j = 0; j < 8; ++j) vx[j] = xb[(size_t)(skg * 8 + j) * N_];

  for (int step = 0; step < 8; ++step) {
    const int c0  = step * 32;
    const int buf = step & 1;
    {
      uint4 u;
      u.x = packbf(vx[0], vx[1]);
      u.y = packbf(vx[2], vx[3]);
      u.z = packbf(vx[4], vx[5]);
      u.w = packbf(vx[6], vx[7]);
      *reinterpret_cast<uint4*>(&s_x[buf][skg * 512 + spx * 8]) = u;
    }
    float vn[8];
    if (step < 7) {
      const int c1 = c0 + 32;
      #pragma unroll
      for (int j = 0; j < 8; ++j) vn[j] = xb[(size_t)(c1 + skg * 8 + j) * N_];
    }
    __syncthreads();
    const short8b bfrag = *reinterpret_cast<const short8b*>(
        &s_x[buf][lg * 512 + (w * 16 + ln15) * 8]);
    #pragma unroll
    for (int ot = 0; ot < 9; ++ot) {
      const short8b afrag = *reinterpret_cast<const short8b*>(
          wbf + (size_t)(ot * 16 + ln15) * C_ + c0 + lg * 8);
      acc[ot] = __builtin_amdgcn_mfma_f32_16x16x32_bf16(afrag, bfrag, acc[ot], 0, 0, 0);
    }
    if (step < 7) {
      #pragma unroll
      for (int j = 0; j < 8; ++j) vx[j] = vn[j];
    }
  }

  float* pb = proj + (size_t)b * OTOT_ * N_ + px0 + w * 16 + ln15;
  #pragma unroll
  for (int ot = 0; ot < 9; ++ot)
    #pragma unroll
    for (int r = 0; r < 4; ++r)
      pb[(size_t)(ot * 16 + lg * 4 + r) * N_] = acc[ot][r];
}

// ---------------------------------------------------------------------------
// K2 v3: GroupNorm stats, float4 loads.
// ---------------------------------------------------------------------------
__global__ __launch_bounds__(256) void k_stats(const float* __restrict__ proj,
    float* __restrict__ meanp, float* __restrict__ rstdp) {
  const int bg = blockIdx.x;           // b*36 + g
  const int b = bg / NG_, g = bg % NG_;
  const float* p = proj + ((size_t)b * OTOT_ + g * 4) * N_;
  float s = 0.f, s2 = 0.f;
  for (int i = threadIdx.x * 4; i < 4 * N_; i += 1024) {
    const float4 v = *reinterpret_cast<const float4*>(p + i);
    s  += v.x + v.y + v.z + v.w;
    s2 += v.x * v.x + v.y * v.y + v.z * v.z + v.w * v.w;
  }
  __shared__ float rs[256], rq[256];
  rs[threadIdx.x] = s; rq[threadIdx.x] = s2;
  __syncthreads();
  for (int off = 128; off > 0; off >>= 1) {
    if (threadIdx.x < off) {
      rs[threadIdx.x] += rs[threadIdx.x + off];
      rq[threadIdx.x] += rq[threadIdx.x + off];
    }
    __syncthreads();
  }
  if (threadIdx.x == 0) {
    float m   = rs[0] * (1.f / 16384.f);
    float var = rq[0] * (1.f / 16384.f) - m * m;
    meanp[bg] = m;
    rstdp[bg] = rsqrtf(var + EPS_);
  }
}

// ---------------------------------------------------------------------------
// K3: k GroupNorm-apply + softmax over n.
// ---------------------------------------------------------------------------
__global__ __launch_bounds__(256) void k_softmax(const float* __restrict__ proj,
    const float* __restrict__ meanp, const float* __restrict__ rstdp,
    const float* __restrict__ gkg, const float* __restrict__ gkb,
    float* __restrict__ ksm) {
  const int bk = blockIdx.x;
  const int b = bk >> 4, kk = bk & 15;
  const int g = 16 + (kk >> 2);
  const float mu = meanp[b * NG_ + g], rs = rstdp[b * NG_ + g];
  const float ga = gkg[kk], be = gkb[kk];
  const float* p = proj + ((size_t)b * OTOT_ + 64 + kk) * N_;
  float* o = ksm + ((size_t)b * KK_ + kk) * N_;

  float xn[16];
  float m = -1e30f;
  #pragma unroll
  for (int i = 0; i < 16; ++i) {
    float v = (p[threadIdx.x + i * 256] - mu) * rs * ga + be;
    xn[i] = v;
    m = fmaxf(m, v);
  }
  __shared__ float red[256];
  red[threadIdx.x] = m; __syncthreads();
  for (int off = 128; off > 0; off >>= 1) {
    if (threadIdx.x < off)
      red[threadIdx.x] = fmaxf(red[threadIdx.x], red[threadIdx.x + off]);
    __syncthreads();
  }
  m = red[0];
  __syncthreads();
  float s = 0.f;
  #pragma unroll
  for (int i = 0; i < 16; ++i) { xn[i] = __expf(xn[i] - m); s += xn[i]; }
  red[threadIdx.x] = s; __syncthreads();
  for (int off = 128; off > 0; off >>= 1) {
    if (threadIdx.x < off) red[threadIdx.x] += red[threadIdx.x + off];
    __syncthreads();
  }
  float inv = 1.f / red[0];
  #pragma unroll
  for (int i = 0; i < 16; ++i) o[threadIdx.x + i * 256] = xn[i] * inv;
}

// ---------------------------------------------------------------------------
// K4 v2: content lambda, float4 loads.
// ---------------------------------------------------------------------------
__global__ __launch_bounds__(256) void k_lam(const float* __restrict__ proj,
    const float* __restrict__ ksm,
    const float* __restrict__ meanp, const float* __restrict__ rstdp,
    const float* __restrict__ gvg, const float* __restrict__ gvb,
    float* __restrict__ lam) {
  const int bv = blockIdx.x;
  const int b = bv >> 6, v = bv & 63;
  const int g = 20 + (v >> 2);
  const float mu = meanp[b * NG_ + g], rs = rstdp[b * NG_ + g];
  const float ga = gvg[v], be = gvb[v];
  const float* pv = proj + ((size_t)b * OTOT_ + 80 + v) * N_;
  const float* pk = ksm + (size_t)b * KK_ * N_;

  float acc[16];
  #pragma unroll
  for (int k = 0; k < 16; ++k) acc[k] = 0.f;
  for (int n = threadIdx.x * 4; n < N_; n += 1024) {
    float4 vn = *reinterpret_cast<const float4*>(pv + n);
    vn.x = (vn.x - mu) * rs * ga + be;
    vn.y = (vn.y - mu) * rs * ga + be;
    vn.z = (vn.z - mu) * rs * ga + be;
    vn.w = (vn.w - mu) * rs * ga + be;
    #pragma unroll
    for (int k = 0; k < 16; ++k) {
      const float4 kv = *reinterpret_cast<const float4*>(pk + (size_t)k * N_ + n);
      acc[k] += kv.x * vn.x + kv.y * vn.y + kv.z * vn.z + kv.w * vn.w;
    }
  }
  __shared__ float red[64];
  const int lane = threadIdx.x & 63, wid = threadIdx.x >> 6;
  #pragma unroll
  for (int k = 0; k < 16; ++k) {
    float s = acc[k];
    #pragma unroll
    for (int off = 32; off > 0; off >>= 1) s += __shfl_down(s, off, 64);
    if (lane == 0) red[wid * 16 + k] = s;
  }
  __syncthreads();
  if (threadIdx.x < 16) {
    float s = red[threadIdx.x] + red[16 + threadIdx.x] +
              red[32 + threadIdx.x] + red[48 + threadIdx.x];
    lam[((size_t)b * KK_ + threadIdx.x) * VV_ + v] = s;
  }
}

// ---------------------------------------------------------------------------
// K-QE: qe[t][n] = sum_k GN(q)[h,k,n]*emb[k,t] once per (b,h,n), bf16 out.
// ---------------------------------------------------------------------------
__global__ __launch_bounds__(256) void k_qe(const float* __restrict__ proj,
    const float* __restrict__ meanp, const float* __restrict__ rstdp,
    const float* __restrict__ gqg, const float* __restrict__ gqb,
    const float* __restrict__ emb, unsigned short* __restrict__ qeb) {
  const int strip = blockIdx.x;   // 16
  const int h     = blockIdx.y;   // 4
  const int b     = blockIdx.z;   // 16
  const int r0    = strip * 4;
  const int tid   = threadIdx.x;
  const int wid   = __builtin_amdgcn_readfirstlane(tid >> 6);  // tap-split
  const int slot  = tid & 63;
  const int ty    = slot >> 4, txg = slot & 15;
  const int x0    = txg << 2;
  const int n0    = (r0 + ty) * W_ + x0;

  const float* pb = proj + (size_t)b * OTOT_ * N_;

  float qn[4][16];
  #pragma unroll
  for (int k = 0; k < 16; ++k) {
    const int o = h * 16 + k, g = o >> 2;
    const float mu = meanp[b * NG_ + g], rs = rstdp[b * NG_ + g];
    const float ga = gqg[o], be = gqb[o];
    const float4 qv = *reinterpret_cast<const float4*>(pb + (size_t)o * N_ + n0);
    qn[0][k] = (qv.x - mu) * rs * ga + be;
    qn[1][k] = (qv.y - mu) * rs * ga + be;
    qn[2][k] = (qv.z - mu) * rs * ga + be;
    qn[3][k] = (qv.w - mu) * rs * ga + be;
  }

  unsigned short* qb = qeb + (size_t)(b * 4 + h) * 49 * N_;
  const int t0 = wid * 13;
  const int t1 = (t0 + 13 < 49) ? (t0 + 13) : 49;
  for (int t = t0; t < t1; ++t) {
    float p0 = 0.f, p1 = 0.f, p2 = 0.f, p3 = 0.f;
    #pragma unroll
    for (int k = 0; k < 16; ++k) {
      const float e = emb[k * 49 + t];   // uniform -> scalar
      p0 += qn[0][k] * e; p1 += qn[1][k] * e;
      p2 += qn[2][k] * e; p3 += qn[3][k] * e;
    }
    uint2 pk;
    pk.x = packbf(p0, p1);
    pk.y = packbf(p2, p3);
    *reinterpret_cast<uint2*>(&qb[(size_t)t * N_ + n0]) = pk;
  }
}

// ---------------------------------------------------------------------------
// K5 v10 (R17 proven): conv+combine, vsplit=8, qe bulk-prefetch into LDS.
// Phase order stage -> barrier -> content+conv is the proven optimum
// (R15 and R19 both showed moving work across the barrier regresses).
// ---------------------------------------------------------------------------
__global__ __launch_bounds__(256) void k_final_v10(const float* __restrict__ proj,
    const float* __restrict__ meanp, const float* __restrict__ rstdp,
    const float* __restrict__ gqg, const float* __restrict__ gqb,
    const float* __restrict__ gvg, const float* __restrict__ gvb,
    const unsigned short* __restrict__ qeb, const float* __restrict__ lam,
    float* __restrict__ out) {
  const int wgid = (blockIdx.x & 7) * 1024 + (blockIdx.x >> 3);
  const int b     = wgid >> 9;          // 0..15
  const int r2    = wgid & 511;
  const int h     = r2 & 3;
  const int strip = (r2 >> 2) & 15;
  const int s     = r2 >> 6;            // v-set 0..7 (8 channels each)

  const int r0    = strip * 4;
  const int tid   = threadIdx.x;
  const int vlane = __builtin_amdgcn_readfirstlane(tid >> 6);
  const int slot  = tid & 63;
  const int ty    = slot >> 4;
  const int txg   = slot & 15;
  const int x0    = txg << 2;
  const int n0    = (r0 + ty) * W_ + x0;
  const int pos4  = ty * 64 + x0;

  __shared__ unsigned short s_qe[49 * 256];   // bf16 qe[t][pos], 24.5 KB
  __shared__ unsigned short s_v[8 * 720];     // bf16 v[ch][10][72], 11.25 KB
  __shared__ float s_mu[NG_], s_rs[NG_];
  __shared__ float s_gvw[64], s_gvb[64];

  // phase 0: constants + zero the 2 pad columns of s_v
  if (tid < NG_) { s_mu[tid] = meanp[b * NG_ + tid]; s_rs[tid] = rstdp[b * NG_ + tid]; }
  else if (tid >= 64 && tid < 128) { s_gvw[tid - 64] = gvg[tid - 64]; s_gvb[tid - 64] = gvb[tid - 64]; }
  for (int i = tid; i < 160; i += 256) {
    const int vh = i / 20, rem = i % 20;
    const int ry = rem >> 1, side = rem & 1;
    uint2 z; z.x = 0u; z.y = 0u;
    *reinterpret_cast<uint2*>(&s_v[vh * 720 + ry * 72 + side * 68]) = z;
  }
  __syncthreads();

  const float* pb = proj + (size_t)b * OTOT_ * N_;

  // phase 1a: bulk-prefetch qe tile (49 taps x 256 px) into s_qe, coalesced.
  {
    const unsigned short* qb = qeb + (size_t)(b * 4 + h) * 49 * N_ + r0 * 64;
    for (int i = tid; i < 1568; i += 256) {
      const int t = i >> 5;          // tap
      const int r = i & 31;          // 16B chunk within the 512B tap row
      const uint4 d = *reinterpret_cast<const uint4*>(&qb[(size_t)t * N_ + r * 8]);
      *reinterpret_cast<uint4*>(&s_qe[t * 256 + r * 8]) = d;
    }
  }

  // phase 1b: stage this block's 8-ch v-set. Thread = (half, ch8, rx4);
  // each thread does 5 rows. Division-free.
  {
    const int half = tid >> 7;           // 0..1 -> rows 0-4 / 5-9
    const int vh   = (tid >> 4) & 7;     // 0..7
    const int rx4  = (tid & 15) + 1;     // 1..16
    const int gx0  = (rx4 << 2) - 4;
    const int v    = s * 8 + vh;
    const int g    = 20 + (v >> 2);
    const float mu = s_mu[g], rs = s_rs[g], ga = s_gvw[v], be = s_gvb[v];
    const float* src = pb + (size_t)(80 + v) * N_ + gx0;
    unsigned short* dst = &s_v[vh * 720 + (rx4 << 2)];
    #pragma unroll
    for (int rr = 0; rr < 5; ++rr) {
      const int ry = half * 5 + rr;
      const int gy = r0 - 3 + ry;
      float4 f = make_float4(0.f, 0.f, 0.f, 0.f);
      if (gy >= 0 && gy < H_) {
        f = *reinterpret_cast<const float4*>(src + (size_t)gy * W_);
        f.x = (f.x - mu) * rs * ga + be;
        f.y = (f.y - mu) * rs * ga + be;
        f.z = (f.z - mu) * rs * ga + be;
        f.w = (f.w - mu) * rs * ga + be;
      }
      uint2 w;
      w.x = packbf(f.x, f.y);
      w.y = packbf(f.z, f.w);
      *reinterpret_cast<uint2*>(dst + ry * 72) = w;
    }
  }
  __syncthreads();   // the one hot barrier

  // phase 2: content (k-outer, GN on the fly, scalar lam) + conv (all-LDS)
  float acc[2][4];
  #pragma unroll
  for (int vj = 0; vj < 2; ++vj)
    #pragma unroll
    for (int p = 0; p < 4; ++p) acc[vj][p] = 0.f;

  const float* lb = lam + (size_t)b * 1024;
  #pragma unroll
  for (int k = 0; k < 16; ++k) {
    const int o = h * 16 + k, g = o >> 2;
    const float mu = s_mu[g], rs = s_rs[g];
    const float ga = gqg[o], be = gqb[o];   // uniform -> scalar
    const float4 qv = *reinterpret_cast<const float4*>(pb + (size_t)o * N_ + n0);
    const float q0 = (qv.x - mu) * rs * ga + be;
    const float q1 = (qv.y - mu) * rs * ga + be;
    const float q2 = (qv.z - mu) * rs * ga + be;
    const float q3 = (qv.w - mu) * rs * ga + be;
    #pragma unroll
    for (int vj = 0; vj < 2; ++vj) {
      const int v = __builtin_amdgcn_readfirstlane(s * 8 + vj * 4 + vlane);
      const float lv = lb[k * 64 + v];      // uniform -> scalar
      acc[vj][0] += q0 * lv; acc[vj][1] += q1 * lv;
      acc[vj][2] += q2 * lv; acc[vj][3] += q3 * lv;
    }
  }

  #pragma unroll
  for (int i = 0; i < 7; ++i) {
    float qeu[7][4];
    #pragma unroll
    for (int j = 0; j < 7; ++j) {
      const uint2 pk = *reinterpret_cast<const uint2*>(&s_qe[(i * 7 + j) * 256 + pos4]);
      qeu[j][0] = bflo(pk.x); qeu[j][1] = bfhi(pk.x);
      qeu[j][2] = bflo(pk.y); qeu[j][3] = bfhi(pk.y);
    }
    #pragma unroll
    for (int vj = 0; vj < 2; ++vj) {
      const int vh = vj * 4 + vlane;
      const unsigned short* sv = &s_v[vh * 720 + (ty + i) * 72 + x0];
      const uint2 wa = *reinterpret_cast<const uint2*>(sv);
      const uint2 wb = *reinterpret_cast<const uint2*>(sv + 4);
      const uint2 wc = *reinterpret_cast<const uint2*>(sv + 8);
      float wv[12];
      wv[0] = bflo(wa.x); wv[1] = bfhi(wa.x); wv[2]  = bflo(wa.y); wv[3]  = bfhi(wa.y);
      wv[4] = bflo(wb.x); wv[5] = bfhi(wb.x); wv[6]  = bflo(wb.y); wv[7]  = bfhi(wb.y);
      wv[8] = bflo(wc.x); wv[9] = bfhi(wc.x); wv[10] = bflo(wc.y); wv[11] = bfhi(wc.y);
      #pragma unroll
      for (int j = 0; j < 7; ++j)
        #pragma unroll
        for (int p = 0; p < 4; ++p)
          acc[vj][p] += qeu[j][p] * wv[p + j + 1];
    }
  }

  #pragma unroll
  for (int vj = 0; vj < 2; ++vj) {
    const int v = s * 8 + vj * 4 + vlane;
    float4 o4 = make_float4(acc[vj][0], acc[vj][1], acc[vj][2], acc[vj][3]);
    *reinterpret_cast<float4*>(out + ((size_t)b * 256 + h * 64 + v) * N_ + n0) = o4;
  }
}

// ---------------------------------------------------------------------------
extern "C" void kernel_launch(void* const* d_in, const int* in_sizes, int n_in,
                              void* d_out, int out_size, void* d_ws, size_t ws_size,
                              hipStream_t stream) {
  const float* x   = (const float*)d_in[0];
  const float* wq  = (const float*)d_in[1];
  const float* gqg = (const float*)d_in[2];
  const float* gqb = (const float*)d_in[3];
  const float* wk  = (const float*)d_in[4];
  const float* gkg = (const float*)d_in[5];
  const float* gkb = (const float*)d_in[6];
  const float* wv  = (const float*)d_in[7];
  const float* gvg = (const float*)d_in[8];
  const float* gvb = (const float*)d_in[9];
  const float* emb = (const float*)d_in[10];
  float* out = (float*)d_out;
  float* ws  = (float*)d_ws;

  float* proj  = ws;                                    // B*144*N floats
  float* meanp = proj + (size_t)B_ * OTOT_ * N_;        // B*36
  float* rstdp = meanp + B_ * NG_;                      // B*36
  float* ksm   = rstdp + B_ * NG_;                      // B*16*N
  float* lam   = ksm + (size_t)B_ * KK_ * N_;           // B*16*64
  unsigned short* qeb = (unsigned short*)(lam + (size_t)B_ * KK_ * VV_);
  unsigned short* wbf = qeb + (size_t)B_ * HEADS_ * 49 * N_;

  k_wcvt<<<dim3(144), 256, 0, stream>>>(wq, wk, wv, wbf);
  k_proj_mfma<<<dim3(64, B_), 256, 0, stream>>>(x, wbf, proj);
  k_stats<<<dim3(B_ * NG_), 256, 0, stream>>>(proj, meanp, rstdp);
  k_softmax<<<dim3(B_ * KK_), 256, 0, stream>>>(proj, meanp, rstdp, gkg, gkb, ksm);
  k_lam<<<dim3(B_ * VV_), 256, 0, stream>>>(proj, ksm, meanp, rstdp, gvg, gvb, lam);
  k_qe<<<dim3(16, HEADS_, B_), 256, 0, stream>>>(proj, meanp, rstdp, gqg, gqb, emb, qeb);
  k_final_v10<<<dim3(8192), 256, 0, stream>>>(proj, meanp, rstdp,
      gqg, gqb, gvg, gvb, qeb, lam, out);
}

// Round 21
// 166.123 us; speedup vs baseline: 1.1835x; 1.0270x over previous
//
#include <hip/hip_runtime.h>
#include <math.h>

#define B_    16
#define C_    256
#define H_    64
#define W_    64
#define N_    4096
#define HEADS_ 4
#define KK_   16
#define VV_   64
#define M_    7
#define PAD_  3
#define OTOT_ 144   // 64 q + 16 k + 64 v channels
#define NG_   36    // 36 groups of 4 channels
#define EPS_  1e-5f

typedef __attribute__((ext_vector_type(8))) short short8b;
typedef __attribute__((ext_vector_type(4))) float f32x4;

// bf16 helpers (round-half-up; error ~2^-9 relative, fine vs threshold)
__device__ inline unsigned packbf(float a, float b) {
  unsigned ua = __float_as_uint(a) + 0x8000u;
  unsigned ub = __float_as_uint(b) + 0x8000u;
  return (ua >> 16) | (ub & 0xffff0000u);
}
__device__ inline float bflo(unsigned u) { return __uint_as_float(u << 16); }
__device__ inline float bfhi(unsigned u) { return __uint_as_float(u & 0xffff0000u); }

// ---------------------------------------------------------------------------
// K0: convert wq/wk/wv -> bf16 wbf[144][256] (row-major o-major).
// ---------------------------------------------------------------------------
__global__ __launch_bounds__(256) void k_wcvt(const float* __restrict__ wq,
    const float* __restrict__ wk, const float* __restrict__ wv,
    unsigned short* __restrict__ wbf) {
  const int idx = blockIdx.x * 256 + threadIdx.x;   // grid 144 -> 36864
  if (idx >= OTOT_ * C_) return;
  const int o = idx >> 8, c = idx & 255;
  const float* wrow = (o < 64) ? (wq + o * C_)
                     : ((o < 80) ? (wk + (o - 64) * C_) : (wv + (o - 80) * C_));
  wbf[idx] = (unsigned short)((__float_as_uint(wrow[c]) + 0x8000u) >> 16);
}

// ---------------------------------------------------------------------------
// K1 v7 (R17 proven): MFMA projection GEMM, register-prefetch pipeline.
// ---------------------------------------------------------------------------
__global__ __launch_bounds__(256) void k_proj_mfma(const float* __restrict__ x,
    const unsigned short* __restrict__ wbf, float* __restrict__ proj) {
  const int pt = blockIdx.x;       // 0..63 px-tile (64 px)
  const int b  = blockIdx.y;
  const int px0 = pt * 64;
  const int tid = threadIdx.x;
  const int w    = tid >> 6;       // wave id
  const int lane = tid & 63;
  const int ln15 = lane & 15;
  const int lg   = lane >> 4;      // k-group 0..3

  __shared__ unsigned short s_x[2][2048];   // [buf][kg*512 + px*8]

  const int spx = tid & 63;
  const int skg = tid >> 6;
  const float* xb = x + (size_t)b * C_ * N_ + px0 + spx;

  f32x4 acc[9];
  #pragma unroll
  for (int t = 0; t < 9; ++t) acc[t] = (f32x4){0.f, 0.f, 0.f, 0.f};

  float vx[8];
  #pragma unroll
  for (int j = 0; j < 8; ++j) vx[j] = xb[(size_t)(skg * 8 + j) * N_];

  for (int step = 0; step < 8; ++step) {
    const int c0  = step * 32;
    const int buf = step & 1;
    {
      uint4 u;
      u.x = packbf(vx[0], vx[1]);
      u.y = packbf(vx[2], vx[3]);
      u.z = packbf(vx[4], vx[5]);
      u.w = packbf(vx[6], vx[7]);
      *reinterpret_cast<uint4*>(&s_x[buf][skg * 512 + spx * 8]) = u;
    }
    float vn[8];
    if (step < 7) {
      const int c1 = c0 + 32;
      #pragma unroll
      for (int j = 0; j < 8; ++j) vn[j] = xb[(size_t)(c1 + skg * 8 + j) * N_];
    }
    __syncthreads();
    const short8b bfrag = *reinterpret_cast<const short8b*>(
        &s_x[buf][lg * 512 + (w * 16 + ln15) * 8]);
    #pragma unroll
    for (int ot = 0; ot < 9; ++ot) {
      const short8b afrag = *reinterpret_cast<const short8b*>(
          wbf + (size_t)(ot * 16 + ln15) * C_ + c0 + lg * 8);
      acc[ot] = __builtin_amdgcn_mfma_f32_16x16x32_bf16(afrag, bfrag, acc[ot], 0, 0, 0);
    }
    if (step < 7) {
      #pragma unroll
      for (int j = 0; j < 8; ++j) vx[j] = vn[j];
    }
  }

  float* pb = proj + (size_t)b * OTOT_ * N_ + px0 + w * 16 + ln15;
  #pragma unroll
  for (int ot = 0; ot < 9; ++ot)
    #pragma unroll
    for (int r = 0; r < 4; ++r)
      pb[(size_t)(ot * 16 + lg * 4 + r) * N_] = acc[ot][r];
}

// ---------------------------------------------------------------------------
// K2 v3: GroupNorm stats, float4 loads.
// ---------------------------------------------------------------------------
__global__ __launch_bounds__(256) void k_stats(const float* __restrict__ proj,
    float* __restrict__ meanp, float* __restrict__ rstdp) {
  const int bg = blockIdx.x;           // b*36 + g
  const int b = bg / NG_, g = bg % NG_;
  const float* p = proj + ((size_t)b * OTOT_ + g * 4) * N_;
  float s = 0.f, s2 = 0.f;
  for (int i = threadIdx.x * 4; i < 4 * N_; i += 1024) {
    const float4 v = *reinterpret_cast<const float4*>(p + i);
    s  += v.x + v.y + v.z + v.w;
    s2 += v.x * v.x + v.y * v.y + v.z * v.z + v.w * v.w;
  }
  __shared__ float rs[256], rq[256];
  rs[threadIdx.x] = s; rq[threadIdx.x] = s2;
  __syncthreads();
  for (int off = 128; off > 0; off >>= 1) {
    if (threadIdx.x < off) {
      rs[threadIdx.x] += rs[threadIdx.x + off];
      rq[threadIdx.x] += rq[threadIdx.x + off];
    }
    __syncthreads();
  }
  if (threadIdx.x == 0) {
    float m   = rs[0] * (1.f / 16384.f);
    float var = rq[0] * (1.f / 16384.f) - m * m;
    meanp[bg] = m;
    rstdp[bg] = rsqrtf(var + EPS_);
  }
}

// ---------------------------------------------------------------------------
// K3: k GroupNorm-apply + softmax over n.
// ---------------------------------------------------------------------------
__global__ __launch_bounds__(256) void k_softmax(const float* __restrict__ proj,
    const float* __restrict__ meanp, const float* __restrict__ rstdp,
    const float* __restrict__ gkg, const float* __restrict__ gkb,
    float* __restrict__ ksm) {
  const int bk = blockIdx.x;
  const int b = bk >> 4, kk = bk & 15;
  const int g = 16 + (kk >> 2);
  const float mu = meanp[b * NG_ + g], rs = rstdp[b * NG_ + g];
  const float ga = gkg[kk], be = gkb[kk];
  const float* p = proj + ((size_t)b * OTOT_ + 64 + kk) * N_;
  float* o = ksm + ((size_t)b * KK_ + kk) * N_;

  float xn[16];
  float m = -1e30f;
  #pragma unroll
  for (int i = 0; i < 16; ++i) {
    float v = (p[threadIdx.x + i * 256] - mu) * rs * ga + be;
    xn[i] = v;
    m = fmaxf(m, v);
  }
  __shared__ float red[256];
  red[threadIdx.x] = m; __syncthreads();
  for (int off = 128; off > 0; off >>= 1) {
    if (threadIdx.x < off)
      red[threadIdx.x] = fmaxf(red[threadIdx.x], red[threadIdx.x + off]);
    __syncthreads();
  }
  m = red[0];
  __syncthreads();
  float s = 0.f;
  #pragma unroll
  for (int i = 0; i < 16; ++i) { xn[i] = __expf(xn[i] - m); s += xn[i]; }
  red[threadIdx.x] = s; __syncthreads();
  for (int off = 128; off > 0; off >>= 1) {
    if (threadIdx.x < off) red[threadIdx.x] += red[threadIdx.x + off];
    __syncthreads();
  }
  float inv = 1.f / red[0];
  #pragma unroll
  for (int i = 0; i < 16; ++i) o[threadIdx.x + i * 256] = xn[i] * inv;
}

// ---------------------------------------------------------------------------
// K4 v2: content lambda, float4 loads.
// ---------------------------------------------------------------------------
__global__ __launch_bounds__(256) void k_lam(const float* __restrict__ proj,
    const float* __restrict__ ksm,
    const float* __restrict__ meanp, const float* __restrict__ rstdp,
    const float* __restrict__ gvg, const float* __restrict__ gvb,
    float* __restrict__ lam) {
  const int bv = blockIdx.x;
  const int b = bv >> 6, v = bv & 63;
  const int g = 20 + (v >> 2);
  const float mu = meanp[b * NG_ + g], rs = rstdp[b * NG_ + g];
  const float ga = gvg[v], be = gvb[v];
  const float* pv = proj + ((size_t)b * OTOT_ + 80 + v) * N_;
  const float* pk = ksm + (size_t)b * KK_ * N_;

  float acc[16];
  #pragma unroll
  for (int k = 0; k < 16; ++k) acc[k] = 0.f;
  for (int n = threadIdx.x * 4; n < N_; n += 1024) {
    float4 vn = *reinterpret_cast<const float4*>(pv + n);
    vn.x = (vn.x - mu) * rs * ga + be;
    vn.y = (vn.y - mu) * rs * ga + be;
    vn.z = (vn.z - mu) * rs * ga + be;
    vn.w = (vn.w - mu) * rs * ga + be;
    #pragma unroll
    for (int k = 0; k < 16; ++k) {
      const float4 kv = *reinterpret_cast<const float4*>(pk + (size_t)k * N_ + n);
      acc[k] += kv.x * vn.x + kv.y * vn.y + kv.z * vn.z + kv.w * vn.w;
    }
  }
  __shared__ float red[64];
  const int lane = threadIdx.x & 63, wid = threadIdx.x >> 6;
  #pragma unroll
  for (int k = 0; k < 16; ++k) {
    float s = acc[k];
    #pragma unroll
    for (int off = 32; off > 0; off >>= 1) s += __shfl_down(s, off, 64);
    if (lane == 0) red[wid * 16 + k] = s;
  }
  __syncthreads();
  if (threadIdx.x < 16) {
    float s = red[threadIdx.x] + red[16 + threadIdx.x] +
              red[32 + threadIdx.x] + red[48 + threadIdx.x];
    lam[((size_t)b * KK_ + threadIdx.x) * VV_ + v] = s;
  }
}

// ---------------------------------------------------------------------------
// K-QE: qe[t][n] = sum_k GN(q)[h,k,n]*emb[k,t] once per (b,h,n), bf16 out.
// ---------------------------------------------------------------------------
__global__ __launch_bounds__(256) void k_qe(const float* __restrict__ proj,
    const float* __restrict__ meanp, const float* __restrict__ rstdp,
    const float* __restrict__ gqg, const float* __restrict__ gqb,
    const float* __restrict__ emb, unsigned short* __restrict__ qeb) {
  const int strip = blockIdx.x;   // 16
  const int h     = blockIdx.y;   // 4
  const int b     = blockIdx.z;   // 16
  const int r0    = strip * 4;
  const int tid   = threadIdx.x;
  const int wid   = __builtin_amdgcn_readfirstlane(tid >> 6);  // tap-split
  const int slot  = tid & 63;
  const int ty    = slot >> 4, txg = slot & 15;
  const int x0    = txg << 2;
  const int n0    = (r0 + ty) * W_ + x0;

  const float* pb = proj + (size_t)b * OTOT_ * N_;

  float qn[4][16];
  #pragma unroll
  for (int k = 0; k < 16; ++k) {
    const int o = h * 16 + k, g = o >> 2;
    const float mu = meanp[b * NG_ + g], rs = rstdp[b * NG_ + g];
    const float ga = gqg[o], be = gqb[o];
    const float4 qv = *reinterpret_cast<const float4*>(pb + (size_t)o * N_ + n0);
    qn[0][k] = (qv.x - mu) * rs * ga + be;
    qn[1][k] = (qv.y - mu) * rs * ga + be;
    qn[2][k] = (qv.z - mu) * rs * ga + be;
    qn[3][k] = (qv.w - mu) * rs * ga + be;
  }

  unsigned short* qb = qeb + (size_t)(b * 4 + h) * 49 * N_;
  const int t0 = wid * 13;
  const int t1 = (t0 + 13 < 49) ? (t0 + 13) : 49;
  for (int t = t0; t < t1; ++t) {
    float p0 = 0.f, p1 = 0.f, p2 = 0.f, p3 = 0.f;
    #pragma unroll
    for (int k = 0; k < 16; ++k) {
      const float e = emb[k * 49 + t];   // uniform -> scalar
      p0 += qn[0][k] * e; p1 += qn[1][k] * e;
      p2 += qn[2][k] * e; p3 += qn[3][k] * e;
    }
    uint2 pk;
    pk.x = packbf(p0, p1);
    pk.y = packbf(p2, p3);
    *reinterpret_cast<uint2*>(&qb[(size_t)t * N_ + n0]) = pk;
  }
}

// ---------------------------------------------------------------------------
// K5 v12: v10's per-thread code, scaled to 512 threads / 16 v-channels.
// qe prefetch + content q-loads amortize over 2x outputs; LDS 47.7 KB ->
// 3 blocks/CU x 8 waves = 24 waves/CU (vs v10's 16). Wave w owns channels
// {s*16+w, s*16+8+w}. Grid 4096, XCD-chunked. Same phase order as v10.
// ---------------------------------------------------------------------------
__global__ __launch_bounds__(512) void k_final_v12(const float* __restrict__ proj,
    const float* __restrict__ meanp, const float* __restrict__ rstdp,
    const float* __restrict__ gqg, const float* __restrict__ gqb,
    const float* __restrict__ gvg, const float* __restrict__ gvb,
    const unsigned short* __restrict__ qeb, const float* __restrict__ lam,
    float* __restrict__ out) {
  const int wgid = (blockIdx.x & 7) * 512 + (blockIdx.x >> 3);
  const int b     = wgid >> 8;          // 0..15
  const int r2    = wgid & 255;
  const int h     = r2 & 3;
  const int strip = (r2 >> 2) & 15;
  const int s     = r2 >> 6;            // v-set 0..3 (16 channels each)

  const int r0    = strip * 4;
  const int tid   = threadIdx.x;
  const int wv_   = __builtin_amdgcn_readfirstlane(tid >> 6);  // wave 0..7
  const int slot  = tid & 63;
  const int ty    = slot >> 4;
  const int txg   = slot & 15;
  const int x0    = txg << 2;
  const int n0    = (r0 + ty) * W_ + x0;
  const int pos4  = ty * 64 + x0;

  __shared__ unsigned short s_qe[49 * 256];   // bf16 qe[t][pos], 24.5 KB
  __shared__ unsigned short s_v[16 * 720];    // bf16 v[ch][10][72], 22.5 KB
  __shared__ float s_mu[NG_], s_rs[NG_];
  __shared__ float s_gvw[64], s_gvb[64];

  // phase 0: constants + zero the 2 pad columns of s_v
  if (tid < NG_) { s_mu[tid] = meanp[b * NG_ + tid]; s_rs[tid] = rstdp[b * NG_ + tid]; }
  else if (tid >= 64 && tid < 128) { s_gvw[tid - 64] = gvg[tid - 64]; s_gvb[tid - 64] = gvb[tid - 64]; }
  if (tid >= 128 && tid < 448) {
    const int i = tid - 128;             // 0..319 = 16ch x 20 pad slots
    const int vh = i / 20, rem = i % 20;
    const int ry = rem >> 1, side = rem & 1;
    uint2 z; z.x = 0u; z.y = 0u;
    *reinterpret_cast<uint2*>(&s_v[vh * 720 + ry * 72 + side * 68]) = z;
  }
  __syncthreads();

  const float* pb = proj + (size_t)b * OTOT_ * N_;

  // phase 1a: bulk-prefetch qe tile (49 taps x 256 px) into s_qe, coalesced.
  {
    const unsigned short* qb = qeb + (size_t)(b * 4 + h) * 49 * N_ + r0 * 64;
    for (int i = tid; i < 1568; i += 512) {
      const int t = i >> 5;          // tap
      const int r = i & 31;          // 16B chunk within the 512B tap row
      const uint4 d = *reinterpret_cast<const uint4*>(&qb[(size_t)t * N_ + r * 8]);
      *reinterpret_cast<uint4*>(&s_qe[t * 256 + r * 8]) = d;
    }
  }

  // phase 1b: stage this block's 16-ch v-set. Thread = (half, ch16, rx4);
  // each thread does 5 rows. Division-free.
  {
    const int half = tid >> 8;           // 0..1 -> rows 0-4 / 5-9
    const int vh   = (tid >> 4) & 15;    // 0..15
    const int rx4  = (tid & 15) + 1;     // 1..16
    const int gx0  = (rx4 << 2) - 4;
    const int v    = s * 16 + vh;
    const int g    = 20 + (v >> 2);
    const float mu = s_mu[g], rs = s_rs[g], ga = s_gvw[v], be = s_gvb[v];
    const float* src = pb + (size_t)(80 + v) * N_ + gx0;
    unsigned short* dst = &s_v[vh * 720 + (rx4 << 2)];
    #pragma unroll
    for (int rr = 0; rr < 5; ++rr) {
      const int ry = half * 5 + rr;
      const int gy = r0 - 3 + ry;
      float4 f = make_float4(0.f, 0.f, 0.f, 0.f);
      if (gy >= 0 && gy < H_) {
        f = *reinterpret_cast<const float4*>(src + (size_t)gy * W_);
        f.x = (f.x - mu) * rs * ga + be;
        f.y = (f.y - mu) * rs * ga + be;
        f.z = (f.z - mu) * rs * ga + be;
        f.w = (f.w - mu) * rs * ga + be;
      }
      uint2 w;
      w.x = packbf(f.x, f.y);
      w.y = packbf(f.z, f.w);
      *reinterpret_cast<uint2*>(dst + ry * 72) = w;
    }
  }
  __syncthreads();   // the one hot barrier

  // phase 2: content (k-outer, GN on the fly, scalar lam) + conv (all-LDS)
  float acc[2][4];
  #pragma unroll
  for (int vj = 0; vj < 2; ++vj)
    #pragma unroll
    for (int p = 0; p < 4; ++p) acc[vj][p] = 0.f;

  const float* lb = lam + (size_t)b * 1024;
  #pragma unroll
  for (int k = 0; k < 16; ++k) {
    const int o = h * 16 + k, g = o >> 2;
    const float mu = s_mu[g], rs = s_rs[g];
    const float ga = gqg[o], be = gqb[o];   // uniform -> scalar
    const float4 qv = *reinterpret_cast<const float4*>(pb + (size_t)o * N_ + n0);
    const float q0 = (qv.x - mu) * rs * ga + be;
    const float q1 = (qv.y - mu) * rs * ga + be;
    const float q2 = (qv.z - mu) * rs * ga + be;
    const float q3 = (qv.w - mu) * rs * ga + be;
    #pragma unroll
    for (int vj = 0; vj < 2; ++vj) {
      const int v = __builtin_amdgcn_readfirstlane(s * 16 + vj * 8 + wv_);
      const float lv = lb[k * 64 + v];      // uniform -> scalar
      acc[vj][0] += q0 * lv; acc[vj][1] += q1 * lv;
      acc[vj][2] += q2 * lv; acc[vj][3] += q3 * lv;
    }
  }

  #pragma unroll
  for (int i = 0; i < 7; ++i) {
    float qeu[7][4];
    #pragma unroll
    for (int j = 0; j < 7; ++j) {
      const uint2 pk = *reinterpret_cast<const uint2*>(&s_qe[(i * 7 + j) * 256 + pos4]);
      qeu[j][0] = bflo(pk.x); qeu[j][1] = bfhi(pk.x);
      qeu[j][2] = bflo(pk.y); qeu[j][3] = bfhi(pk.y);
    }
    #pragma unroll
    for (int vj = 0; vj < 2; ++vj) {
      const int vh = vj * 8 + wv_;
      const unsigned short* sv = &s_v[vh * 720 + (ty + i) * 72 + x0];
      const uint2 wa = *reinterpret_cast<const uint2*>(sv);
      const uint2 wb = *reinterpret_cast<const uint2*>(sv + 4);
      const uint2 wc = *reinterpret_cast<const uint2*>(sv + 8);
      float wvv[12];
      wvv[0] = bflo(wa.x); wvv[1] = bfhi(wa.x); wvv[2]  = bflo(wa.y); wvv[3]  = bfhi(wa.y);
      wvv[4] = bflo(wb.x); wvv[5] = bfhi(wb.x); wvv[6]  = bflo(wb.y); wvv[7]  = bfhi(wb.y);
      wvv[8] = bflo(wc.x); wvv[9] = bfhi(wc.x); wvv[10] = bflo(wc.y); wvv[11] = bfhi(wc.y);
      #pragma unroll
      for (int j = 0; j < 7; ++j)
        #pragma unroll
        for (int p = 0; p < 4; ++p)
          acc[vj][p] += qeu[j][p] * wvv[p + j + 1];
    }
  }

  #pragma unroll
  for (int vj = 0; vj < 2; ++vj) {
    const int v = s * 16 + vj * 8 + wv_;
    float4 o4 = make_float4(acc[vj][0], acc[vj][1], acc[vj][2], acc[vj][3]);
    *reinterpret_cast<float4*>(out + ((size_t)b * 256 + h * 64 + v) * N_ + n0) = o4;
  }
}

// ---------------------------------------------------------------------------
extern "C" void kernel_launch(void* const* d_in, const int* in_sizes, int n_in,
                              void* d_out, int out_size, void* d_ws, size_t ws_size,
                              hipStream_t stream) {
  const float* x   = (const float*)d_in[0];
  const float* wq  = (const float*)d_in[1];
  const float* gqg = (const float*)d_in[2];
  const float* gqb = (const float*)d_in[3];
  const float* wk  = (const float*)d_in[4];
  const float* gkg = (const float*)d_in[5];
  const float* gkb = (const float*)d_in[6];
  const float* wv  = (const float*)d_in[7];
  const float* gvg = (const float*)d_in[8];
  const float* gvb = (const float*)d_in[9];
  const float* emb = (const float*)d_in[10];
  float* out = (float*)d_out;
  float* ws  = (float*)d_ws;

  float* proj  = ws;                                    // B*144*N floats
  float* meanp = proj + (size_t)B_ * OTOT_ * N_;        // B*36
  float* rstdp = meanp + B_ * NG_;                      // B*36
  float* ksm   = rstdp + B_ * NG_;                      // B*16*N
  float* lam   = ksm + (size_t)B_ * KK_ * N_;           // B*16*64
  unsigned short* qeb = (unsigned short*)(lam + (size_t)B_ * KK_ * VV_);
  unsigned short* wbf = qeb + (size_t)B_ * HEADS_ * 49 * N_;

  k_wcvt<<<dim3(144), 256, 0, stream>>>(wq, wk, wv, wbf);
  k_proj_mfma<<<dim3(64, B_), 256, 0, stream>>>(x, wbf, proj);
  k_stats<<<dim3(B_ * NG_), 256, 0, stream>>>(proj, meanp, rstdp);
  k_softmax<<<dim3(B_ * KK_), 256, 0, stream>>>(proj, meanp, rstdp, gkg, gkb, ksm);
  k_lam<<<dim3(B_ * VV_), 256, 0, stream>>>(proj, ksm, meanp, rstdp, gvg, gvb, lam);
  k_qe<<<dim3(16, HEADS_, B_), 256, 0, stream>>>(proj, meanp, rstdp, gqg, gqb, emb, qeb);
  k_final_v12<<<dim3(4096), 512, 0, stream>>>(proj, meanp, rstdp,
      gqg, gqb, gvg, gvb, qeb, lam, out);
}